// Round 1
// baseline (499.698 us; speedup 1.0000x reference)
//
#include <hip/hip_runtime.h>
#include <math.h>

// ---------------------------------------------------------------------------
// SimVQ forward:
//   Q = emb @ W^T + b            [16384,512]  (codebook projection)
//   c_n = Q / max(||Q||,1e-12)   (row L2 norm)
//   idx[m] = argmax_k (z[m] . c_n[k])   (== reference argmin of -(z_n.c_n)*scale)
//   out = z + (Q[idx]-z);  vq_loss = 1.25 * mean((Q[idx]-z)^2)
//
// Precision: fp16 hi/lo split (x ~= hi + lo*2^-11, lo stored *2^11) with two
// f32 MFMA accumulators (hh, cross) -> ~fp32-accurate dots at fp16 MFMA rate.
// ---------------------------------------------------------------------------

typedef _Float16 f16;
typedef _Float16 f16x8 __attribute__((ext_vector_type(8)));
typedef _Float16 f16x4 __attribute__((ext_vector_type(4)));
typedef float f32x4 __attribute__((ext_vector_type(4)));
typedef unsigned int u32;

#define M_TOK   8192      // 8*1024 z rows
#define N_CODE  16384
#define D_DIM   512
#define INV2048 (1.0f/2048.0f)

// ---- workspace layout (bytes) ----
#define OFF_Q    0u            // 16384*512*4 = 33554432
#define OFF_CHI  33554432u     // 16384*512*2 = 16777216
#define OFF_CLO  50331648u
#define OFF_ZHI  67108864u     // 8192*512*2 = 8388608
#define OFF_ZLO  75497472u
#define OFF_EHI  83886080u     // emb splits (dead after codebook GEMM)
#define OFF_ELO  100663296u
#define OFF_WHI  117440512u    // 512*512*2
#define OFF_WLO  117964800u
#define OFF_PVAL OFF_EHI       // alias: 8192*128*4 partial argmax vals
#define OFF_PIDX OFF_ELO       // alias: partial argmax indices
#define OFF_RL   118489088u    // 8192*4 per-row loss

// LDS tile offsets (bytes). 128 rows x 64 f16 (128B/row) per tile.
#define LDS_AHI 0
#define LDS_ALO 16384
#define LDS_BHI 32768
#define LDS_BLO 49152

__device__ __forceinline__ void gload_lds16(const void* g, void* l) {
  __builtin_amdgcn_global_load_lds(
      (const __attribute__((address_space(1))) u32*)g,
      (__attribute__((address_space(3))) u32*)l, 16, 0, 0);
}

// Stage R x 64 f16 tile (row stride in global = 512 f16 = 1024B) into LDS.
// XOR swizzle: physical 16B slot s of row r holds logical k8 = s ^ (r&7).
// LDS dest is linear (wave-uniform base + lane*16) as global_load_lds requires;
// the swizzle is applied on the GLOBAL source address (both-sides rule).
template<int R>
__device__ __forceinline__ void stage_tile(const f16* __restrict__ src, int row0,
                                           int kt, char* lds, int tid) {
#pragma unroll
  for (int i = 0; i < R / 32; ++i) {
    int lin = i * 256 + tid;      // 16B chunk index
    int row = lin >> 3;           // 8 chunks per 128B row
    int slot = lin & 7;
    int k8 = slot ^ (row & 7);
    const char* g = (const char*)src + (((size_t)(row0 + row)) << 10)
                    + (size_t)(kt * 128 + k8 * 16);
    gload_lds16(g, lds + lin * 16);
  }
}

// Core: C[128x128] tile of A[M,512] . B[N,512]^T with hi/lo fp16 split.
// 4 waves in 2x2 grid, each wave 64x64 via 4x4 16x16x32_f16 frags.
__device__ __forceinline__ void gemm_128x128(
    const f16* __restrict__ Ahi, const f16* __restrict__ Alo,
    const f16* __restrict__ Bhi, const f16* __restrict__ Blo,
    int m0, int n0, char* lds, int tid,
    f32x4 (&hh)[4][4], f32x4 (&xx)[4][4]) {
  const int l = tid & 63;
  const int wid = tid >> 6;
  const int wr = (wid >> 1) * 64;
  const int wc = (wid & 1) * 64;

#pragma unroll
  for (int a = 0; a < 4; ++a)
#pragma unroll
    for (int b = 0; b < 4; ++b) {
      hh[a][b] = (f32x4){0.f, 0.f, 0.f, 0.f};
      xx[a][b] = (f32x4){0.f, 0.f, 0.f, 0.f};
    }

  for (int kt = 0; kt < 8; ++kt) {   // K = 512, BK = 64
    stage_tile<128>(Ahi, m0, kt, lds + LDS_AHI, tid);
    stage_tile<128>(Alo, m0, kt, lds + LDS_ALO, tid);
    stage_tile<128>(Bhi, n0, kt, lds + LDS_BHI, tid);
    stage_tile<128>(Blo, n0, kt, lds + LDS_BLO, tid);
    __syncthreads();   // implies vmcnt(0) drain of global_load_lds

#pragma unroll
    for (int ks = 0; ks < 2; ++ks) {
      const int kg = ks * 4 + (l >> 4);   // 16B slot along K
      f16x8 ahi[4], alo[4];
#pragma unroll
      for (int mf = 0; mf < 4; ++mf) {
        int r = wr + mf * 16 + (l & 15);
        int off = r * 128 + ((kg ^ (r & 7)) * 16);
        ahi[mf] = *(const f16x8*)(lds + LDS_AHI + off);
        alo[mf] = *(const f16x8*)(lds + LDS_ALO + off);
      }
#pragma unroll
      for (int nf = 0; nf < 4; ++nf) {
        int r = wc + nf * 16 + (l & 15);
        int off = r * 128 + ((kg ^ (r & 7)) * 16);
        f16x8 bhi = *(const f16x8*)(lds + LDS_BHI + off);
        f16x8 blo = *(const f16x8*)(lds + LDS_BLO + off);
#pragma unroll
        for (int mf = 0; mf < 4; ++mf) {
          hh[mf][nf] = __builtin_amdgcn_mfma_f32_16x16x32_f16(ahi[mf], bhi, hh[mf][nf], 0, 0, 0);
          xx[mf][nf] = __builtin_amdgcn_mfma_f32_16x16x32_f16(ahi[mf], blo, xx[mf][nf], 0, 0, 0);
          xx[mf][nf] = __builtin_amdgcn_mfma_f32_16x16x32_f16(alo[mf], bhi, xx[mf][nf], 0, 0, 0);
        }
      }
    }
    __syncthreads();
  }
}

// ---- codebook GEMM: Q[m0+.., n0+..] = emb . W^T + b ----
__global__ __launch_bounds__(256, 2) void k_gemm_codebook(
    const f16* __restrict__ Ahi, const f16* __restrict__ Alo,
    const f16* __restrict__ Bhi, const f16* __restrict__ Blo,
    const float* __restrict__ bias, float* __restrict__ Q) {
  __shared__ __align__(16) char lds[65536];
  f32x4 hh[4][4], xx[4][4];
  const int tid = threadIdx.x;
  const int m0 = blockIdx.y * 128;
  const int n0 = blockIdx.x * 128;
  gemm_128x128(Ahi, Alo, Bhi, Blo, m0, n0, lds, tid, hh, xx);

  const int l = tid & 63, wid = tid >> 6;
  const int wr = (wid >> 1) * 64, wc = (wid & 1) * 64;
#pragma unroll
  for (int mf = 0; mf < 4; ++mf)
#pragma unroll
    for (int nf = 0; nf < 4; ++nf)
#pragma unroll
      for (int j = 0; j < 4; ++j) {
        int row = m0 + wr + mf * 16 + (l >> 4) * 4 + j;
        int col = n0 + wc + nf * 16 + (l & 15);
        Q[(size_t)row * 512 + col] = hh[mf][nf][j] + xx[mf][nf][j] * INV2048 + bias[col];
      }
}

// ---- scores GEMM + per-128-code-chunk argmax partials ----
__global__ __launch_bounds__(256, 2) void k_gemm_scores(
    const f16* __restrict__ Ahi, const f16* __restrict__ Alo,
    const f16* __restrict__ Bhi, const f16* __restrict__ Blo,
    float* __restrict__ pval, int* __restrict__ pidx) {
  __shared__ __align__(16) char lds[65536];
  f32x4 hh[4][4], xx[4][4];
  const int tid = threadIdx.x;
  const int nblk = blockIdx.x;           // 0..127 code chunks
  const int m0 = blockIdx.y * 128;       // z rows
  const int n0 = nblk * 128;
  gemm_128x128(Ahi, Alo, Bhi, Blo, m0, n0, lds, tid, hh, xx);

  const int l = tid & 63, wid = tid >> 6;
  const int wr = (wid >> 1) * 64, wc = (wid & 1) * 64;
  float* sv = (float*)lds;               // [128 rows][2 wave-cols]
  int* si = (int*)(lds + 1024);

#pragma unroll
  for (int mf = 0; mf < 4; ++mf)
#pragma unroll
    for (int j = 0; j < 4; ++j) {
      float best = -INFINITY;
      int bi = 0x7fffffff;
#pragma unroll
      for (int nf = 0; nf < 4; ++nf) {   // ascending col -> lowest idx on tie
        float v = hh[mf][nf][j] + xx[mf][nf][j] * INV2048;
        int c = n0 + wc + nf * 16 + (l & 15);
        if (v > best) { best = v; bi = c; }
      }
#pragma unroll
      for (int m = 1; m < 16; m <<= 1) { // reduce over the 16 cols in lane-low
        float ov = __shfl_xor(best, m, 64);
        int oi = __shfl_xor(bi, m, 64);
        if (ov > best || (ov == best && oi < bi)) { best = ov; bi = oi; }
      }
      if ((l & 15) == 0) {
        int rloc = wr + mf * 16 + (l >> 4) * 4 + j;  // 0..127
        sv[rloc * 2 + (wid & 1)] = best;
        si[rloc * 2 + (wid & 1)] = bi;
      }
    }
  __syncthreads();
  if (tid < 128) {
    float v = sv[tid * 2 + 0];
    int ii = si[tid * 2 + 0];
    float v1 = sv[tid * 2 + 1];
    int i1 = si[tid * 2 + 1];
    if (v1 > v || (v1 == v && i1 < ii)) { v = v1; ii = i1; }
    int grow = m0 + tid;
    pval[(size_t)grow * 128 + nblk] = v;
    pidx[(size_t)grow * 128 + nblk] = ii;
  }
}

// ---- f32 -> fp16 hi/lo split (lo pre-scaled by 2^11), 4 elems/thread ----
__global__ __launch_bounds__(256) void k_split(const float* __restrict__ src,
                                               f16* __restrict__ hi,
                                               f16* __restrict__ lo, int n4) {
  int i = blockIdx.x * 256 + threadIdx.x;
  if (i >= n4) return;
  const float4 v = ((const float4*)src)[i];
  f16 h0 = (f16)v.x, h1 = (f16)v.y, h2 = (f16)v.z, h3 = (f16)v.w;
  f16 l0 = (f16)((v.x - (float)h0) * 2048.0f);
  f16 l1 = (f16)((v.y - (float)h1) * 2048.0f);
  f16 l2 = (f16)((v.z - (float)h2) * 2048.0f);
  f16 l3 = (f16)((v.w - (float)h3) * 2048.0f);
  ((f16x4*)hi)[i] = (f16x4){h0, h1, h2, h3};
  ((f16x4*)lo)[i] = (f16x4){l0, l1, l2, l3};
}

// ---- row L2-normalize Q -> c_n, split to hi/lo. One block per code row ----
__global__ __launch_bounds__(256) void k_norm_split(const float* __restrict__ Q,
                                                    f16* __restrict__ chi,
                                                    f16* __restrict__ clo) {
  __shared__ float red[256];
  const int row = blockIdx.x, t = threadIdx.x;
  float q0 = Q[(size_t)row * 512 + t];
  float q1 = Q[(size_t)row * 512 + t + 256];
  red[t] = q0 * q0 + q1 * q1;
  __syncthreads();
  for (int s = 128; s > 0; s >>= 1) {
    if (t < s) red[t] += red[t + s];
    __syncthreads();
  }
  float inv = 1.0f / fmaxf(sqrtf(red[0]), 1e-12f);
  float c0 = q0 * inv, c1 = q1 * inv;
  f16 h0 = (f16)c0, h1 = (f16)c1;
  chi[(size_t)row * 512 + t] = h0;
  chi[(size_t)row * 512 + t + 256] = h1;
  clo[(size_t)row * 512 + t] = (f16)((c0 - (float)h0) * 2048.0f);
  clo[(size_t)row * 512 + t + 256] = (f16)((c1 - (float)h1) * 2048.0f);
}

// ---- final argmax over 128 chunks, gather, straight-through, row loss ----
__global__ __launch_bounds__(256) void k_reduce_gather(
    const float* __restrict__ pval, const int* __restrict__ pidx,
    const float* __restrict__ Q, const float* __restrict__ z,
    float* __restrict__ outq, float* __restrict__ outidx,
    float* __restrict__ rloss) {
  __shared__ float sv[128];
  __shared__ int si[128];
  __shared__ float sl[256];
  const int row = blockIdx.x, t = threadIdx.x;
  if (t < 128) {
    sv[t] = pval[(size_t)row * 128 + t];
    si[t] = pidx[(size_t)row * 128 + t];
  }
  __syncthreads();
  for (int s = 64; s > 0; s >>= 1) {
    if (t < s) {
      float v2 = sv[t + s];
      int i2 = si[t + s];
      if (v2 > sv[t] || (v2 == sv[t] && i2 < si[t])) { sv[t] = v2; si[t] = i2; }
    }
    __syncthreads();
  }
  const int best = si[0];
  float local = 0.f;
#pragma unroll
  for (int c2 = 0; c2 < 2; ++c2) {
    int d = t + c2 * 256;
    float qv = Q[(size_t)best * 512 + d];
    float zv = z[(size_t)row * 512 + d];
    outq[(size_t)row * 512 + d] = zv + (qv - zv);  // straight-through value
    float df = qv - zv;
    local += df * df;
  }
  sl[t] = local;
  __syncthreads();
  for (int s = 128; s > 0; s >>= 1) {
    if (t < s) sl[t] += sl[t + s];
    __syncthreads();
  }
  if (t == 0) {
    rloss[row] = sl[0];
    outidx[row] = (float)best;
  }
}

__global__ __launch_bounds__(256) void k_loss_final(const float* __restrict__ rloss,
                                                    float* __restrict__ out_loss) {
  __shared__ float sl[256];
  int t = threadIdx.x;
  float s = 0.f;
#pragma unroll
  for (int i = 0; i < 32; ++i) s += rloss[t + i * 256];
  sl[t] = s;
  __syncthreads();
  for (int k = 128; k > 0; k >>= 1) {
    if (t < k) sl[t] += sl[t + k];
    __syncthreads();
  }
  if (t == 0) out_loss[0] = 1.25f * sl[0] / 4194304.0f;  // commit + 0.25*codebook
}

extern "C" void kernel_launch(void* const* d_in, const int* in_sizes, int n_in,
                              void* d_out, int out_size, void* d_ws, size_t ws_size,
                              hipStream_t stream) {
  const float* z = (const float*)d_in[0];
  const float* emb = (const float*)d_in[1];
  const float* pw = (const float*)d_in[2];
  const float* pb = (const float*)d_in[3];
  // d_in[4] = scale: argmin-invariant, unused.

  char* ws = (char*)d_ws;
  float* Q = (float*)(ws + OFF_Q);
  f16* chi = (f16*)(ws + OFF_CHI);
  f16* clo = (f16*)(ws + OFF_CLO);
  f16* zhi = (f16*)(ws + OFF_ZHI);
  f16* zlo = (f16*)(ws + OFF_ZLO);
  f16* ehi = (f16*)(ws + OFF_EHI);
  f16* elo = (f16*)(ws + OFF_ELO);
  f16* whi = (f16*)(ws + OFF_WHI);
  f16* wlo = (f16*)(ws + OFF_WLO);
  float* pval = (float*)(ws + OFF_PVAL);
  int* pidx = (int*)(ws + OFF_PIDX);
  float* rloss = (float*)(ws + OFF_RL);

  float* outq = (float*)d_out;                 // [8192*512]
  float* outloss = outq + 4194304;             // [1]
  float* outidx = outq + 4194305;              // [8192] (as float values)

  k_split<<<8192, 256, 0, stream>>>(emb, ehi, elo, 2097152);
  k_split<<<4096, 256, 0, stream>>>(z, zhi, zlo, 1048576);
  k_split<<<256, 256, 0, stream>>>(pw, whi, wlo, 65536);
  k_gemm_codebook<<<dim3(4, 128), 256, 0, stream>>>(ehi, elo, whi, wlo, pb, Q);
  k_norm_split<<<16384, 256, 0, stream>>>(Q, chi, clo);
  k_gemm_scores<<<dim3(128, 64), 256, 0, stream>>>(zhi, zlo, chi, clo, pval, pidx);
  k_reduce_gather<<<8192, 256, 0, stream>>>(pval, pidx, Q, z, outq, outidx, rloss);
  k_loss_final<<<1, 256, 0, stream>>>(rloss, outloss);
}

// Round 2
// 336.172 us; speedup vs baseline: 1.4864x; 1.4864x over previous
//
#include <hip/hip_runtime.h>
#include <math.h>

// ---------------------------------------------------------------------------
// SimVQ forward, round 2: bf16 coarse scores (1 MFMA) + exact f64 rescore.
//   Q = emb @ W^T + b              (fp16 hi/lo split GEMM, fp32-exact)
//   c = bf16(Q / ||Q||), z_n = bf16(z / ||z||)
//   coarse[k][m] = c . z_n  (bf16 MFMA, codes-as-rows)  -> top-4 per 128-chunk
//   candidates = entries within 0.010 of coarse max  -> exact f64 rescore
//   out = z + (Q[best]-z); vq_loss = 1.25 * mean((Q[best]-z)^2)
// ---------------------------------------------------------------------------

typedef _Float16 f16;
typedef _Float16 f16x8 __attribute__((ext_vector_type(8)));
typedef _Float16 f16x4 __attribute__((ext_vector_type(4)));
typedef short s16x8 __attribute__((ext_vector_type(8)));
typedef float f32x4 __attribute__((ext_vector_type(4)));
typedef unsigned int u32;
typedef unsigned long long u64;
typedef unsigned short ushort_t;

#define INV2048 (1.0f/2048.0f)
#define MARGIN  0.010f

// ---- workspace layout (bytes) ----
#define OFF_Q    0u            // 16384*512*4 = 33554432
#define OFF_EHI  33554432u     // emb hi f16 (dead after codebook GEMM)
#define OFF_ELO  50331648u     // emb lo f16 (dead after codebook GEMM)
#define OFF_WHI  67108864u     // 512*512*2
#define OFF_WLO  67633152u
#define OFF_CB   68157440u     // codebook bf16 normalized, 16384*512*2
#define OFF_ZB   84934656u     // z normalized bf16, 8192*512*2
#define OFF_RL   93323264u     // 8192*4 per-row loss
#define OFF_PK   OFF_EHI       // alias: top-4 keys, 8192*128*4*8 = 33554432

__device__ __forceinline__ void gload_lds16(const void* g, void* l) {
  __builtin_amdgcn_global_load_lds(
      (const __attribute__((address_space(1))) u32*)g,
      (__attribute__((address_space(3))) u32*)l, 16, 0, 0);
}

// Stage 128 x 64 elems of 2-byte data (global row stride 1024B) into LDS.
// XOR swizzle on the GLOBAL source (both-sides rule); LDS dest linear.
__device__ __forceinline__ void stage_tile(const void* __restrict__ src, int row0,
                                           int kt, char* lds, int tid) {
#pragma unroll
  for (int i = 0; i < 4; ++i) {
    int lin = i * 256 + tid;      // 16B chunk index
    int row = lin >> 3;           // 8 chunks per 128B row
    int slot = lin & 7;
    int k8 = slot ^ (row & 7);
    const char* g = (const char*)src + (((size_t)(row0 + row)) << 10)
                    + (size_t)(kt * 128 + k8 * 16);
    gload_lds16(g, lds + lin * 16);
  }
}

// ---- u64 sort keys: high 32 = ordered float, low 32 = ~idx (tie->low idx) ----
__device__ __forceinline__ u64 make_key(float v, int idx) {
  u32 b = __float_as_uint(v);
  u32 m = (u32)((int)b >> 31) | 0x80000000u;
  return ((u64)(b ^ m) << 32) | (u32)(0x7FFFFFFF - idx);
}
__device__ __forceinline__ float key_val(u64 k) {
  u32 o = (u32)(k >> 32);
  u32 m = (o & 0x80000000u) ? 0x80000000u : 0xFFFFFFFFu;
  return __uint_as_float(o ^ m);
}
__device__ __forceinline__ int key_idx(u64 k) {
  return 0x7FFFFFFF - (int)(u32)(k & 0xFFFFFFFFu);
}
__device__ __forceinline__ u64 umax64(u64 a, u64 b) { return a > b ? a : b; }
__device__ __forceinline__ u64 umin64(u64 a, u64 b) { return a < b ? a : b; }

__device__ __forceinline__ void ins_top4(u64* k, u64 x) {
  if (x > k[1]) {
    k[3] = k[2]; k[2] = k[1];
    if (x > k[0]) { k[1] = k[0]; k[0] = x; } else k[1] = x;
  } else if (x > k[3]) {
    if (x > k[2]) { k[3] = k[2]; k[2] = x; } else k[3] = x;
  }
}

// top-4 of two sorted-desc 4-lists (a in place, b aux): bitonic select + sort
__device__ __forceinline__ void merge_top4(u64* a, const u64* b) {
  u64 s0 = umax64(a[0], b[3]);
  u64 s1 = umax64(a[1], b[2]);
  u64 s2 = umax64(a[2], b[1]);
  u64 s3 = umax64(a[3], b[0]);
  u64 t0 = umax64(s0, s2), t2 = umin64(s0, s2);
  u64 t1 = umax64(s1, s3), t3 = umin64(s1, s3);
  a[0] = umax64(t0, t1); a[1] = umin64(t0, t1);
  a[2] = umax64(t2, t3); a[3] = umin64(t2, t3);
}

// ======================= exact fp16 hi/lo GEMM (codebook) ====================
#define LDS_AHI 0
#define LDS_ALO 16384
#define LDS_BHI 32768
#define LDS_BLO 49152

__global__ __launch_bounds__(256, 2) void k_gemm_codebook(
    const f16* __restrict__ Ahi, const f16* __restrict__ Alo,
    const f16* __restrict__ Bhi, const f16* __restrict__ Blo,
    const float* __restrict__ bias, float* __restrict__ Q) {
  __shared__ __align__(16) char lds[65536];
  f32x4 hh[4][4], xx[4][4];
  const int tid = threadIdx.x;
  const int m0 = blockIdx.y * 128;
  const int n0 = blockIdx.x * 128;
  const int l = tid & 63;
  const int wid = tid >> 6;
  const int wr = (wid >> 1) * 64;
  const int wc = (wid & 1) * 64;

#pragma unroll
  for (int a = 0; a < 4; ++a)
#pragma unroll
    for (int b = 0; b < 4; ++b) {
      hh[a][b] = (f32x4){0.f, 0.f, 0.f, 0.f};
      xx[a][b] = (f32x4){0.f, 0.f, 0.f, 0.f};
    }

  for (int kt = 0; kt < 8; ++kt) {
    stage_tile(Ahi, m0, kt, lds + LDS_AHI, tid);
    stage_tile(Alo, m0, kt, lds + LDS_ALO, tid);
    stage_tile(Bhi, n0, kt, lds + LDS_BHI, tid);
    stage_tile(Blo, n0, kt, lds + LDS_BLO, tid);
    __syncthreads();
#pragma unroll
    for (int ks = 0; ks < 2; ++ks) {
      const int kg = ks * 4 + (l >> 4);
      f16x8 ahi[4], alo[4];
#pragma unroll
      for (int mf = 0; mf < 4; ++mf) {
        int r = wr + mf * 16 + (l & 15);
        int off = r * 128 + ((kg ^ (r & 7)) * 16);
        ahi[mf] = *(const f16x8*)(lds + LDS_AHI + off);
        alo[mf] = *(const f16x8*)(lds + LDS_ALO + off);
      }
#pragma unroll
      for (int nf = 0; nf < 4; ++nf) {
        int r = wc + nf * 16 + (l & 15);
        int off = r * 128 + ((kg ^ (r & 7)) * 16);
        f16x8 bhi = *(const f16x8*)(lds + LDS_BHI + off);
        f16x8 blo = *(const f16x8*)(lds + LDS_BLO + off);
#pragma unroll
        for (int mf = 0; mf < 4; ++mf) {
          hh[mf][nf] = __builtin_amdgcn_mfma_f32_16x16x32_f16(ahi[mf], bhi, hh[mf][nf], 0, 0, 0);
          xx[mf][nf] = __builtin_amdgcn_mfma_f32_16x16x32_f16(ahi[mf], blo, xx[mf][nf], 0, 0, 0);
          xx[mf][nf] = __builtin_amdgcn_mfma_f32_16x16x32_f16(alo[mf], bhi, xx[mf][nf], 0, 0, 0);
        }
      }
    }
    __syncthreads();
  }

#pragma unroll
  for (int mf = 0; mf < 4; ++mf)
#pragma unroll
    for (int nf = 0; nf < 4; ++nf)
#pragma unroll
      for (int j = 0; j < 4; ++j) {
        int row = m0 + wr + mf * 16 + (l >> 4) * 4 + j;
        int col = n0 + wc + nf * 16 + (l & 15);
        Q[(size_t)row * 512 + col] = hh[mf][nf][j] + xx[mf][nf][j] * INV2048 + bias[col];
      }
}

// ======================= bf16 coarse GEMM + top-4 epilogue ===================
// A = codebook bf16 [16384][512] (rows), B = z_n bf16 [8192][512] (cols).
// C[code][z]: per z-col, each lane holds 16 code-scores -> cheap top-4.
__global__ __launch_bounds__(256, 3) void k_gemm_coarse(
    const ushort_t* __restrict__ CB, const ushort_t* __restrict__ ZB,
    u64* __restrict__ pk) {
  __shared__ __align__(16) char lds[32768];
  f32x4 acc[4][4];
  const int tid = threadIdx.x;
  const int cb0 = blockIdx.x * 128;   // code rows
  const int zb0 = blockIdx.y * 128;   // z cols
  const int l = tid & 63;
  const int wid = tid >> 6;
  const int wr = (wid >> 1);          // code half (0/1)
  const int wc = (wid & 1);           // z half (0/1)

#pragma unroll
  for (int a = 0; a < 4; ++a)
#pragma unroll
    for (int b = 0; b < 4; ++b) acc[a][b] = (f32x4){0.f, 0.f, 0.f, 0.f};

  for (int kt = 0; kt < 8; ++kt) {
    stage_tile(CB, cb0, kt, lds, tid);           // A tile 16KB
    stage_tile(ZB, zb0, kt, lds + 16384, tid);   // B tile 16KB
    __syncthreads();
#pragma unroll
    for (int ks = 0; ks < 2; ++ks) {
      const int kg = ks * 4 + (l >> 4);
      s16x8 af[4];
#pragma unroll
      for (int mf = 0; mf < 4; ++mf) {
        int r = wr * 64 + mf * 16 + (l & 15);
        af[mf] = *(const s16x8*)(lds + r * 128 + ((kg ^ (r & 7)) * 16));
      }
#pragma unroll
      for (int nf = 0; nf < 4; ++nf) {
        int r = wc * 64 + nf * 16 + (l & 15);
        s16x8 bf = *(const s16x8*)(lds + 16384 + r * 128 + ((kg ^ (r & 7)) * 16));
#pragma unroll
        for (int mf = 0; mf < 4; ++mf)
          acc[mf][nf] = __builtin_amdgcn_mfma_f32_16x16x32_bf16(af[mf], bf, acc[mf][nf], 0, 0, 0);
      }
    }
    __syncthreads();
  }

  // ---- epilogue: per z-col top-4 over this block's 128 codes ----
  // lane l holds, for each nf, 16 values (mf x j) of z-col wc*64+nf*16+(l&15),
  // codes cb0 + wr*64 + mf*16 + (l>>4)*4 + j.
  u64* eld = (u64*)lds;   // [128 cols][2 wr][4]
  __syncthreads();        // tiles dead, reuse LDS

#pragma unroll
  for (int nf = 0; nf < 4; ++nf) {
    u64 k4[4] = {0, 0, 0, 0};
#pragma unroll
    for (int mf = 0; mf < 4; ++mf)
#pragma unroll
      for (int j = 0; j < 4; ++j) {
        int code = cb0 + wr * 64 + mf * 16 + (l >> 4) * 4 + j;
        ins_top4(k4, make_key(acc[mf][nf][j], code));
      }
    // merge across the 4 lanes sharing this z-col (xor 16, then 32)
#pragma unroll
    for (int mk = 16; mk <= 32; mk <<= 1) {
      u64 o[4];
#pragma unroll
      for (int s = 0; s < 4; ++s)
        o[s] = (u64)__shfl_xor((long long)k4[s], mk);
      merge_top4(k4, o);
    }
    if ((l >> 4) == 0) {
      int col = wc * 64 + nf * 16 + l;
#pragma unroll
      for (int s = 0; s < 4; ++s) eld[(col * 2 + wr) * 4 + s] = k4[s];
    }
  }
  __syncthreads();

  if (tid < 128) {
    u64 a[4], b[4];
#pragma unroll
    for (int s = 0; s < 4; ++s) { a[s] = eld[(tid * 2 + 0) * 4 + s]; b[s] = eld[(tid * 2 + 1) * 4 + s]; }
    merge_top4(a, b);
    size_t base = (((size_t)(zb0 + tid)) * 128 + blockIdx.x) * 4;
#pragma unroll
    for (int s = 0; s < 4; ++s) pk[base + s] = a[s];
  }
}

// ---- f32 -> fp16 hi/lo split ----
__global__ __launch_bounds__(256) void k_split(const float* __restrict__ src,
                                               f16* __restrict__ hi,
                                               f16* __restrict__ lo, int n4) {
  int i = blockIdx.x * 256 + threadIdx.x;
  if (i >= n4) return;
  const float4 v = ((const float4*)src)[i];
  f16 h0 = (f16)v.x, h1 = (f16)v.y, h2 = (f16)v.z, h3 = (f16)v.w;
  ((f16x4*)hi)[i] = (f16x4){h0, h1, h2, h3};
  ((f16x4*)lo)[i] = (f16x4){(f16)((v.x - (float)h0) * 2048.0f),
                            (f16)((v.y - (float)h1) * 2048.0f),
                            (f16)((v.z - (float)h2) * 2048.0f),
                            (f16)((v.w - (float)h3) * 2048.0f)};
}

__device__ __forceinline__ ushort_t f2bf_rne(float f) {
  u32 b = __float_as_uint(f);
  b += 0x7FFFu + ((b >> 16) & 1u);
  return (ushort_t)(b >> 16);
}

// ---- row L2-normalize src -> bf16 dst. One block per row, 512 cols ----
__global__ __launch_bounds__(256) void k_norm_bf16(const float* __restrict__ src,
                                                   ushort_t* __restrict__ dst) {
  __shared__ float red[256];
  const int row = blockIdx.x, t = threadIdx.x;
  float q0 = src[(size_t)row * 512 + t];
  float q1 = src[(size_t)row * 512 + t + 256];
  red[t] = q0 * q0 + q1 * q1;
  __syncthreads();
  for (int s = 128; s > 0; s >>= 1) {
    if (t < s) red[t] += red[t + s];
    __syncthreads();
  }
  float inv = 1.0f / fmaxf(sqrtf(red[0]), 1e-12f);
  dst[(size_t)row * 512 + t] = f2bf_rne(q0 * inv);
  dst[(size_t)row * 512 + t + 256] = f2bf_rne(q1 * inv);
}

// ---- candidate rescore (f64) + gather + straight-through + row loss ----
__global__ __launch_bounds__(256) void k_rescore_gather(
    const u64* __restrict__ pk, const float* __restrict__ Q,
    const float* __restrict__ z, float* __restrict__ outq,
    float* __restrict__ outidx, float* __restrict__ rloss) {
  __shared__ float sz[512];
  __shared__ double redd[8];
  __shared__ u64 redk[4];
  __shared__ int cand[64];
  __shared__ int ccount;
  const int row = blockIdx.x, t = threadIdx.x;

  sz[t] = z[(size_t)row * 512 + t];
  sz[t + 256] = z[(size_t)row * 512 + t + 256];
  if (t == 0) ccount = 0;

  u64 k1 = pk[(size_t)row * 512 + t * 2];
  u64 k2 = pk[(size_t)row * 512 + t * 2 + 1];
  u64 km = umax64(k1, k2);
  for (int m = 1; m < 64; m <<= 1)
    km = umax64(km, (u64)__shfl_xor((long long)km, m));
  if ((t & 63) == 0) redk[t >> 6] = km;
  __syncthreads();
  u64 gk = umax64(umax64(redk[0], redk[1]), umax64(redk[2], redk[3]));
  float thresh = key_val(gk) - MARGIN;

  if (key_val(k1) >= thresh) { int p = atomicAdd(&ccount, 1); if (p < 64) cand[p] = key_idx(k1); }
  if (key_val(k2) >= thresh) { int p = atomicAdd(&ccount, 1); if (p < 64) cand[p] = key_idx(k2); }
  __syncthreads();
  int nc = ccount < 64 ? ccount : 64;

  double bs = -1e300;
  int bi = 0x7FFFFFFF;
  for (int c = 0; c < nc; ++c) {
    int code = cand[c];
    const float* Qr = Q + (size_t)code * 512;
    double dotp = 0.0, qq = 0.0;
#pragma unroll
    for (int h = 0; h < 2; ++h) {
      int d = t + h * 256;
      double qv = (double)Qr[d];
      dotp += (double)sz[d] * qv;
      qq += qv * qv;
    }
    for (int m = 1; m < 64; m <<= 1) {
      dotp += __shfl_xor(dotp, m);
      qq += __shfl_xor(qq, m);
    }
    if ((t & 63) == 0) { redd[t >> 6] = dotp; redd[4 + (t >> 6)] = qq; }
    __syncthreads();
    double dsum = redd[0] + redd[1] + redd[2] + redd[3];
    double qsum = redd[4] + redd[5] + redd[6] + redd[7];
    double s = dsum / fmax(sqrt(qsum), 1e-12);
    if (s > bs || (s == bs && code < bi)) { bs = s; bi = code; }
    __syncthreads();
  }

  const float* Qb = Q + (size_t)bi * 512;
  double lsum = 0.0;
#pragma unroll
  for (int h = 0; h < 2; ++h) {
    int d = t + h * 256;
    float qv = Qb[d], zv = sz[d];
    outq[(size_t)row * 512 + d] = zv + (qv - zv);
    float df = qv - zv;
    lsum += (double)df * (double)df;
  }
  for (int m = 1; m < 64; m <<= 1) lsum += __shfl_xor(lsum, m);
  if ((t & 63) == 0) redd[t >> 6] = lsum;
  __syncthreads();
  if (t == 0) {
    rloss[row] = (float)(redd[0] + redd[1] + redd[2] + redd[3]);
    outidx[row] = (float)bi;
  }
}

__global__ __launch_bounds__(256) void k_loss_final(const float* __restrict__ rloss,
                                                    float* __restrict__ out_loss) {
  __shared__ float sl[256];
  int t = threadIdx.x;
  float s = 0.f;
#pragma unroll
  for (int i = 0; i < 32; ++i) s += rloss[t + i * 256];
  sl[t] = s;
  __syncthreads();
  for (int k = 128; k > 0; k >>= 1) {
    if (t < k) sl[t] += sl[t + k];
    __syncthreads();
  }
  if (t == 0) out_loss[0] = 1.25f * sl[0] / 4194304.0f;
}

extern "C" void kernel_launch(void* const* d_in, const int* in_sizes, int n_in,
                              void* d_out, int out_size, void* d_ws, size_t ws_size,
                              hipStream_t stream) {
  const float* z = (const float*)d_in[0];
  const float* emb = (const float*)d_in[1];
  const float* pw = (const float*)d_in[2];
  const float* pb = (const float*)d_in[3];

  char* ws = (char*)d_ws;
  float* Q = (float*)(ws + OFF_Q);
  f16* ehi = (f16*)(ws + OFF_EHI);
  f16* elo = (f16*)(ws + OFF_ELO);
  f16* whi = (f16*)(ws + OFF_WHI);
  f16* wlo = (f16*)(ws + OFF_WLO);
  ushort_t* cb = (ushort_t*)(ws + OFF_CB);
  ushort_t* zb = (ushort_t*)(ws + OFF_ZB);
  u64* pk = (u64*)(ws + OFF_PK);
  float* rloss = (float*)(ws + OFF_RL);

  float* outq = (float*)d_out;
  float* outloss = outq + 4194304;
  float* outidx = outq + 4194305;

  k_split<<<8192, 256, 0, stream>>>(emb, ehi, elo, 2097152);
  k_split<<<256, 256, 0, stream>>>(pw, whi, wlo, 65536);
  k_norm_bf16<<<8192, 256, 0, stream>>>(z, zb);                    // z_n bf16
  k_gemm_codebook<<<dim3(4, 128), 256, 0, stream>>>(ehi, elo, whi, wlo, pb, Q);
  k_norm_bf16<<<16384, 256, 0, stream>>>(Q, cb);                   // c_n bf16
  k_gemm_coarse<<<dim3(128, 64), 256, 0, stream>>>(cb, zb, pk);
  k_rescore_gather<<<8192, 256, 0, stream>>>(pk, Q, z, outq, outidx, rloss);
  k_loss_final<<<1, 256, 0, stream>>>(rloss, outloss);
}

// Round 3
// 296.625 us; speedup vs baseline: 1.6846x; 1.1333x over previous
//
#include <hip/hip_runtime.h>
#include <math.h>

// ---------------------------------------------------------------------------
// SimVQ forward, round 3: VALU-cut round.
//  - coarse epilogue: per-chunk max + within-margin collect (supersedes top-4
//    insertion sort; provable superset of global candidates, ~8x fewer VALU)
//  - LDS fragment addressing hoisted: base + mf*2048 compile-time immediates
// ---------------------------------------------------------------------------

typedef _Float16 f16;
typedef _Float16 f16x8 __attribute__((ext_vector_type(8)));
typedef _Float16 f16x4 __attribute__((ext_vector_type(4)));
typedef short s16x8 __attribute__((ext_vector_type(8)));
typedef float f32x4 __attribute__((ext_vector_type(4)));
typedef unsigned int u32;
typedef unsigned long long u64;
typedef unsigned short ushort_t;

#define INV2048 (1.0f/2048.0f)
#define MARGIN  0.010f

// ---- workspace layout (bytes) ----
#define OFF_Q    0u            // 16384*512*4 = 33554432
#define OFF_EHI  33554432u     // emb hi f16 (dead after codebook GEMM)
#define OFF_ELO  50331648u     // emb lo f16 (dead after codebook GEMM)
#define OFF_WHI  67108864u     // 512*512*2
#define OFF_WLO  67633152u
#define OFF_CB   68157440u     // codebook bf16 normalized, 16384*512*2
#define OFF_ZB   84934656u     // z normalized bf16, 8192*512*2
#define OFF_RL   93323264u     // 8192*4 per-row loss
#define OFF_PK   OFF_EHI       // alias: cand keys, 8192*128*4*8 = 33554432

__device__ __forceinline__ void gload_lds16(const void* g, void* l) {
  __builtin_amdgcn_global_load_lds(
      (const __attribute__((address_space(1))) u32*)g,
      (__attribute__((address_space(3))) u32*)l, 16, 0, 0);
}

// Stage 128 x 64 elems of 2-byte data (global row stride 1024B) into LDS.
// XOR swizzle on the GLOBAL source (both-sides rule); LDS dest linear.
__device__ __forceinline__ void stage_tile(const void* __restrict__ src, int row0,
                                           int kt, char* lds, int tid) {
#pragma unroll
  for (int i = 0; i < 4; ++i) {
    int lin = i * 256 + tid;      // 16B chunk index
    int row = lin >> 3;           // 8 chunks per 128B row
    int slot = lin & 7;
    int k8 = slot ^ (row & 7);
    const char* g = (const char*)src + (((size_t)(row0 + row)) << 10)
                    + (size_t)(kt * 128 + k8 * 16);
    gload_lds16(g, lds + lin * 16);
  }
}

// ---- u64 sort keys: high 32 = ordered float, low 32 = ~idx (tie->low idx) ----
__device__ __forceinline__ u64 make_key(float v, int idx) {
  u32 b = __float_as_uint(v);
  u32 m = (u32)((int)b >> 31) | 0x80000000u;
  return ((u64)(b ^ m) << 32) | (u32)(0x7FFFFFFF - idx);
}
__device__ __forceinline__ float key_val(u64 k) {
  u32 o = (u32)(k >> 32);
  u32 m = (o & 0x80000000u) ? 0x80000000u : 0xFFFFFFFFu;
  return __uint_as_float(o ^ m);   // key 0 -> NaN (always fails >= thresh)
}
__device__ __forceinline__ int key_idx(u64 k) {
  return 0x7FFFFFFF - (int)(u32)(k & 0xFFFFFFFFu);
}
__device__ __forceinline__ u64 umax64(u64 a, u64 b) { return a > b ? a : b; }

// ======================= exact fp16 hi/lo GEMM (codebook) ====================
#define LDS_AHI 0
#define LDS_ALO 16384
#define LDS_BHI 32768
#define LDS_BLO 49152

__global__ __launch_bounds__(256, 2) void k_gemm_codebook(
    const f16* __restrict__ Ahi, const f16* __restrict__ Alo,
    const f16* __restrict__ Bhi, const f16* __restrict__ Blo,
    const float* __restrict__ bias, float* __restrict__ Q) {
  __shared__ __align__(16) char lds[65536];
  f32x4 hh[4][4], xx[4][4];
  const int tid = threadIdx.x;
  const int m0 = blockIdx.y * 128;
  const int n0 = blockIdx.x * 128;
  const int l = tid & 63;
  const int wid = tid >> 6;
  const int wr = (wid >> 1) * 64;
  const int wc = (wid & 1) * 64;
  const int r7 = (l & 15) & 7;   // low 3 bits of every fragment row (mf*16 == 0 mod 8)

#pragma unroll
  for (int a = 0; a < 4; ++a)
#pragma unroll
    for (int b = 0; b < 4; ++b) {
      hh[a][b] = (f32x4){0.f, 0.f, 0.f, 0.f};
      xx[a][b] = (f32x4){0.f, 0.f, 0.f, 0.f};
    }

  for (int kt = 0; kt < 8; ++kt) {
    stage_tile(Ahi, m0, kt, lds + LDS_AHI, tid);
    stage_tile(Alo, m0, kt, lds + LDS_ALO, tid);
    stage_tile(Bhi, n0, kt, lds + LDS_BHI, tid);
    stage_tile(Blo, n0, kt, lds + LDS_BLO, tid);
    __syncthreads();
#pragma unroll
    for (int ks = 0; ks < 2; ++ks) {
      const int kg = ks * 4 + (l >> 4);
      const int s = (kg ^ r7) * 16;
      const char* pa = lds + (wr + (l & 15)) * 128 + s;   // + mf*2048 immediates
      const char* pb = lds + (wc + (l & 15)) * 128 + s;   // + nf*2048 immediates
      f16x8 ahi[4], alo[4];
#pragma unroll
      for (int mf = 0; mf < 4; ++mf) {
        ahi[mf] = *(const f16x8*)(pa + LDS_AHI + mf * 2048);
        alo[mf] = *(const f16x8*)(pa + LDS_ALO + mf * 2048);
      }
#pragma unroll
      for (int nf = 0; nf < 4; ++nf) {
        f16x8 bhi = *(const f16x8*)(pb + LDS_BHI + nf * 2048);
        f16x8 blo = *(const f16x8*)(pb + LDS_BLO + nf * 2048);
#pragma unroll
        for (int mf = 0; mf < 4; ++mf) {
          hh[mf][nf] = __builtin_amdgcn_mfma_f32_16x16x32_f16(ahi[mf], bhi, hh[mf][nf], 0, 0, 0);
          xx[mf][nf] = __builtin_amdgcn_mfma_f32_16x16x32_f16(ahi[mf], blo, xx[mf][nf], 0, 0, 0);
          xx[mf][nf] = __builtin_amdgcn_mfma_f32_16x16x32_f16(alo[mf], bhi, xx[mf][nf], 0, 0, 0);
        }
      }
    }
    __syncthreads();
  }

#pragma unroll
  for (int mf = 0; mf < 4; ++mf)
#pragma unroll
    for (int nf = 0; nf < 4; ++nf)
#pragma unroll
      for (int j = 0; j < 4; ++j) {
        int row = m0 + wr + mf * 16 + (l >> 4) * 4 + j;
        int col = n0 + wc + nf * 16 + (l & 15);
        Q[(size_t)row * 512 + col] = hh[mf][nf][j] + xx[mf][nf][j] * INV2048 + bias[col];
      }
}

// ======================= bf16 coarse GEMM + candidate epilogue ===============
// A = codebook bf16 [16384][512] (rows), B = z_n bf16 [8192][512] (cols).
// C[code][z]. Epilogue: per z-col chunk max, then collect values within
// MARGIN of it (provable superset of within-margin-of-global-max candidates).
__global__ __launch_bounds__(256, 3) void k_gemm_coarse(
    const ushort_t* __restrict__ CB, const ushort_t* __restrict__ ZB,
    u64* __restrict__ pk) {
  __shared__ __align__(16) char lds[32768];
  f32x4 acc[4][4];
  const int tid = threadIdx.x;
  const int cb0 = blockIdx.x * 128;   // code rows
  const int zb0 = blockIdx.y * 128;   // z cols
  const int l = tid & 63;
  const int wid = tid >> 6;
  const int wr = (wid >> 1);          // code half (0/1)
  const int wc = (wid & 1);           // z half (0/1)
  const int r7 = (l & 15) & 7;

#pragma unroll
  for (int a = 0; a < 4; ++a)
#pragma unroll
    for (int b = 0; b < 4; ++b) acc[a][b] = (f32x4){0.f, 0.f, 0.f, 0.f};

  for (int kt = 0; kt < 8; ++kt) {
    stage_tile(CB, cb0, kt, lds, tid);           // A tile 16KB
    stage_tile(ZB, zb0, kt, lds + 16384, tid);   // B tile 16KB
    __syncthreads();
#pragma unroll
    for (int ks = 0; ks < 2; ++ks) {
      const int kg = ks * 4 + (l >> 4);
      const int s = (kg ^ r7) * 16;
      const char* pa = lds + (wr * 64 + (l & 15)) * 128 + s;
      const char* pb = lds + 16384 + (wc * 64 + (l & 15)) * 128 + s;
      s16x8 af[4];
#pragma unroll
      for (int mf = 0; mf < 4; ++mf)
        af[mf] = *(const s16x8*)(pa + mf * 2048);
#pragma unroll
      for (int nf = 0; nf < 4; ++nf) {
        s16x8 bf = *(const s16x8*)(pb + nf * 2048);
#pragma unroll
        for (int mf = 0; mf < 4; ++mf)
          acc[mf][nf] = __builtin_amdgcn_mfma_f32_16x16x32_bf16(af[mf], bf, acc[mf][nf], 0, 0, 0);
      }
    }
    __syncthreads();
  }

  // ---- epilogue ----
  // lane l holds, for each nf, 16 values (mf x j): z-col wc*64+nf*16+(l&15),
  // code cb0 + wr*64 + mf*16 + (l>>4)*4 + j.
  float* cmax = (float*)lds;            // [128 cols][2 wr halves]
  u32* cnt = (u32*)(lds + 1024);        // [128]
  u64* slots = (u64*)(lds + 2048);      // [128][4]

  // phase A: per-(col, wr-half) max, LDS init
  float cm[4];
#pragma unroll
  for (int nf = 0; nf < 4; ++nf) {
    float m = acc[0][nf][0];
#pragma unroll
    for (int mf = 0; mf < 4; ++mf)
#pragma unroll
      for (int j = 0; j < 4; ++j) m = fmaxf(m, acc[mf][nf][j]);
    m = fmaxf(m, __shfl_xor(m, 16, 64));
    m = fmaxf(m, __shfl_xor(m, 32, 64));
    cm[nf] = m;
  }
  if (tid < 128) cnt[tid] = 0;
  slots[tid] = 0;
  slots[tid + 256] = 0;
  if ((l >> 4) == 0) {
#pragma unroll
    for (int nf = 0; nf < 4; ++nf)
      cmax[(wc * 64 + nf * 16 + l) * 2 + wr] = cm[nf];
  }
  __syncthreads();

  // phase B: collect values within MARGIN of full chunk max
#pragma unroll
  for (int nf = 0; nf < 4; ++nf) {
    int col = wc * 64 + nf * 16 + (l & 15);
    float thresh = fmaxf(cmax[col * 2], cmax[col * 2 + 1]) - MARGIN;
#pragma unroll
    for (int mf = 0; mf < 4; ++mf)
#pragma unroll
      for (int j = 0; j < 4; ++j) {
        float v = acc[mf][nf][j];
        if (v >= thresh) {
          int code = cb0 + wr * 64 + mf * 16 + ((l >> 4) << 2) + j;
          u32 p = atomicAdd(&cnt[col], 1u);
          if (p < 4) slots[col * 4 + p] = make_key(v, code);
        }
      }
  }
  __syncthreads();

  // phase C: write out 4 slots per col
  if (tid < 128) {
    size_t base = (((size_t)(zb0 + tid)) * 128 + blockIdx.x) * 4;
#pragma unroll
    for (int s = 0; s < 4; ++s) pk[base + s] = slots[tid * 4 + s];
  }
}

// ---- f32 -> fp16 hi/lo split ----
__global__ __launch_bounds__(256) void k_split(const float* __restrict__ src,
                                               f16* __restrict__ hi,
                                               f16* __restrict__ lo, int n4) {
  int i = blockIdx.x * 256 + threadIdx.x;
  if (i >= n4) return;
  const float4 v = ((const float4*)src)[i];
  f16 h0 = (f16)v.x, h1 = (f16)v.y, h2 = (f16)v.z, h3 = (f16)v.w;
  ((f16x4*)hi)[i] = (f16x4){h0, h1, h2, h3};
  ((f16x4*)lo)[i] = (f16x4){(f16)((v.x - (float)h0) * 2048.0f),
                            (f16)((v.y - (float)h1) * 2048.0f),
                            (f16)((v.z - (float)h2) * 2048.0f),
                            (f16)((v.w - (float)h3) * 2048.0f)};
}

__device__ __forceinline__ ushort_t f2bf_rne(float f) {
  u32 b = __float_as_uint(f);
  b += 0x7FFFu + ((b >> 16) & 1u);
  return (ushort_t)(b >> 16);
}

// ---- row L2-normalize src -> bf16 dst. One block per row, 512 cols ----
__global__ __launch_bounds__(256) void k_norm_bf16(const float* __restrict__ src,
                                                   ushort_t* __restrict__ dst) {
  __shared__ float red[256];
  const int row = blockIdx.x, t = threadIdx.x;
  float q0 = src[(size_t)row * 512 + t];
  float q1 = src[(size_t)row * 512 + t + 256];
  red[t] = q0 * q0 + q1 * q1;
  __syncthreads();
  for (int s = 128; s > 0; s >>= 1) {
    if (t < s) red[t] += red[t + s];
    __syncthreads();
  }
  float inv = 1.0f / fmaxf(sqrtf(red[0]), 1e-12f);
  dst[(size_t)row * 512 + t] = f2bf_rne(q0 * inv);
  dst[(size_t)row * 512 + t + 256] = f2bf_rne(q1 * inv);
}

// ---- candidate rescore (f64) + gather + straight-through + row loss ----
__global__ __launch_bounds__(256) void k_rescore_gather(
    const u64* __restrict__ pk, const float* __restrict__ Q,
    const float* __restrict__ z, float* __restrict__ outq,
    float* __restrict__ outidx, float* __restrict__ rloss) {
  __shared__ float sz[512];
  __shared__ double redd[8];
  __shared__ u64 redk[4];
  __shared__ int cand[64];
  __shared__ int ccount;
  const int row = blockIdx.x, t = threadIdx.x;

  sz[t] = z[(size_t)row * 512 + t];
  sz[t + 256] = z[(size_t)row * 512 + t + 256];
  if (t == 0) ccount = 0;

  u64 k1 = pk[(size_t)row * 512 + t * 2];
  u64 k2 = pk[(size_t)row * 512 + t * 2 + 1];
  u64 km = umax64(k1, k2);
  for (int m = 1; m < 64; m <<= 1)
    km = umax64(km, (u64)__shfl_xor((long long)km, m));
  if ((t & 63) == 0) redk[t >> 6] = km;
  __syncthreads();
  u64 gk = umax64(umax64(redk[0], redk[1]), umax64(redk[2], redk[3]));
  float thresh = key_val(gk) - MARGIN;

  if (key_val(k1) >= thresh) { int p = atomicAdd(&ccount, 1); if (p < 64) cand[p] = key_idx(k1); }
  if (key_val(k2) >= thresh) { int p = atomicAdd(&ccount, 1); if (p < 64) cand[p] = key_idx(k2); }
  __syncthreads();
  int nc = ccount < 64 ? ccount : 64;

  double bs = -1e300;
  int bi = 0x7FFFFFFF;
  for (int c = 0; c < nc; ++c) {
    int code = cand[c];
    const float* Qr = Q + (size_t)code * 512;
    double dotp = 0.0, qq = 0.0;
#pragma unroll
    for (int h = 0; h < 2; ++h) {
      int d = t + h * 256;
      double qv = (double)Qr[d];
      dotp += (double)sz[d] * qv;
      qq += qv * qv;
    }
    for (int m = 1; m < 64; m <<= 1) {
      dotp += __shfl_xor(dotp, m);
      qq += __shfl_xor(qq, m);
    }
    if ((t & 63) == 0) { redd[t >> 6] = dotp; redd[4 + (t >> 6)] = qq; }
    __syncthreads();
    double dsum = redd[0] + redd[1] + redd[2] + redd[3];
    double qsum = redd[4] + redd[5] + redd[6] + redd[7];
    double s = dsum / fmax(sqrt(qsum), 1e-12);
    if (s > bs || (s == bs && code < bi)) { bs = s; bi = code; }
    __syncthreads();
  }

  const float* Qb = Q + (size_t)bi * 512;
  double lsum = 0.0;
#pragma unroll
  for (int h = 0; h < 2; ++h) {
    int d = t + h * 256;
    float qv = Qb[d], zv = sz[d];
    outq[(size_t)row * 512 + d] = zv + (qv - zv);
    float df = qv - zv;
    lsum += (double)df * (double)df;
  }
  for (int m = 1; m < 64; m <<= 1) lsum += __shfl_xor(lsum, m);
  if ((t & 63) == 0) redd[t >> 6] = lsum;
  __syncthreads();
  if (t == 0) {
    rloss[row] = (float)(redd[0] + redd[1] + redd[2] + redd[3]);
    outidx[row] = (float)bi;
  }
}

__global__ __launch_bounds__(256) void k_loss_final(const float* __restrict__ rloss,
                                                    float* __restrict__ out_loss) {
  __shared__ float sl[256];
  int t = threadIdx.x;
  float s = 0.f;
#pragma unroll
  for (int i = 0; i < 32; ++i) s += rloss[t + i * 256];
  sl[t] = s;
  __syncthreads();
  for (int k = 128; k > 0; k >>= 1) {
    if (t < k) sl[t] += sl[t + k];
    __syncthreads();
  }
  if (t == 0) out_loss[0] = 1.25f * sl[0] / 4194304.0f;
}

extern "C" void kernel_launch(void* const* d_in, const int* in_sizes, int n_in,
                              void* d_out, int out_size, void* d_ws, size_t ws_size,
                              hipStream_t stream) {
  const float* z = (const float*)d_in[0];
  const float* emb = (const float*)d_in[1];
  const float* pw = (const float*)d_in[2];
  const float* pb = (const float*)d_in[3];

  char* ws = (char*)d_ws;
  float* Q = (float*)(ws + OFF_Q);
  f16* ehi = (f16*)(ws + OFF_EHI);
  f16* elo = (f16*)(ws + OFF_ELO);
  f16* whi = (f16*)(ws + OFF_WHI);
  f16* wlo = (f16*)(ws + OFF_WLO);
  ushort_t* cb = (ushort_t*)(ws + OFF_CB);
  ushort_t* zb = (ushort_t*)(ws + OFF_ZB);
  u64* pk = (u64*)(ws + OFF_PK);
  float* rloss = (float*)(ws + OFF_RL);

  float* outq = (float*)d_out;
  float* outloss = outq + 4194304;
  float* outidx = outq + 4194305;

  k_split<<<8192, 256, 0, stream>>>(emb, ehi, elo, 2097152);
  k_split<<<256, 256, 0, stream>>>(pw, whi, wlo, 65536);
  k_norm_bf16<<<8192, 256, 0, stream>>>(z, zb);                    // z_n bf16
  k_gemm_codebook<<<dim3(4, 128), 256, 0, stream>>>(ehi, elo, whi, wlo, pb, Q);
  k_norm_bf16<<<16384, 256, 0, stream>>>(Q, cb);                   // c_n bf16
  k_gemm_coarse<<<dim3(128, 64), 256, 0, stream>>>(cb, zb, pk);
  k_rescore_gather<<<8192, 256, 0, stream>>>(pk, Q, z, outq, outidx, rloss);
  k_loss_final<<<1, 256, 0, stream>>>(rloss, outloss);
}